// Round 2
// baseline (228.020 us; speedup 1.0000x reference)
//
#include <hip/hip_runtime.h>

#define BB 8192
#define TT 512
#define II 5
#define HH 16
#define TC 64
#define NCHUNK (TT / TC)

// DPP row_ror:R within 16-lane rows. Exact direction semantics don't matter:
// we self-calibrate the lane->column map at init (any fixed permutation works
// for a dot product).
template<int R>
__device__ __forceinline__ float rot16(float v) {
    int i = __builtin_bit_cast(int, v);
    int r = __builtin_amdgcn_update_dpp(i, i, 0x120 + R, 0xF, 0xF, false);
    return __builtin_bit_cast(float, r);
}

__device__ __forceinline__ float dot4(float4 a, float4 b, float acc) {
    acc = fmaf(a.x, b.x, acc);
    acc = fmaf(a.y, b.y, acc);
    acc = fmaf(a.z, b.z, acc);
    acc = fmaf(a.w, b.w, acc);
    return acc;
}

__device__ __forceinline__ float fast_sigmoid(float x) {
    float e = __builtin_amdgcn_exp2f(x * -1.4426950408889634f);
    return __builtin_amdgcn_rcpf(1.0f + e);
}

__device__ __forceinline__ float fast_tanh(float x) {
    float e = __builtin_amdgcn_exp2f(x * 2.8853900817779268f);
    return fmaf(-2.0f, __builtin_amdgcn_rcpf(e + 1.0f), 1.0f);
}

__global__ __launch_bounds__(256, 2)
void gru_fwd_kernel(const float* __restrict__ x,
                    const float* __restrict__ W_ih,
                    const float* __restrict__ W_hh,
                    const float* __restrict__ b_ih,
                    const float* __restrict__ b_hh,
                    const float* __restrict__ W_fc,
                    const float* __restrict__ b_fc,
                    float* __restrict__ out) {
    // LDS: only the x chunk (no h buffer, no inner-loop LDS writes/barriers)
    __shared__ float4 lds_x4[16][TC + 1];   // x[b][t][0:4]
    __shared__ float  lds_x1[16][TC + 8];   // x[b][t][4]

    const int tid = threadIdx.x;
    const int g   = tid >> 4;    // local batch 0..15 (aligned with DPP rows)
    const int j   = tid & 15;    // h index 0..15
    const int b0  = blockIdx.x * 16;
    const int b   = b0 + g;

    // ---- self-calibrated rotation column map (direction-agnostic) ----
    float fj = (float)j;
    int col[16];
    col[0] = j;
#define CAL(R) col[R] = (int)rot16<R>(fj);
    CAL(1)  CAL(2)  CAL(3)  CAL(4)  CAL(5)  CAL(6)  CAL(7)
    CAL(8)  CAL(9)  CAL(10) CAL(11) CAL(12) CAL(13) CAL(14) CAL(15)
#undef CAL

    // ---- W_hh rows permuted to rotation order, in registers ----
    const float* Wr = W_hh + (size_t)j * HH;
    const float* Wz = W_hh + (size_t)(HH + j) * HH;
    const float* Wn = W_hh + (size_t)(2 * HH + j) * HH;
    float wr[16], wz[16], wn[16];
#pragma unroll
    for (int r = 0; r < 16; ++r) {
        wr[r] = Wr[col[r]];
        wz[r] = Wz[col[r]];
        wn[r] = Wn[col[r]];
    }

    // ---- W_ih rows ----
    const float* irp = W_ih + (size_t)j * II;
    const float* izp = W_ih + (size_t)(HH + j) * II;
    const float* inp = W_ih + (size_t)(2 * HH + j) * II;
    float4 wir = make_float4(irp[0], irp[1], irp[2], irp[3]); float wir4 = irp[4];
    float4 wiz = make_float4(izp[0], izp[1], izp[2], izp[3]); float wiz4 = izp[4];
    float4 win = make_float4(inp[0], inp[1], inp[2], inp[3]); float win4 = inp[4];

    const float brz = b_ih[j] + b_hh[j];
    const float bzz = b_ih[HH + j] + b_hh[HH + j];
    const float bxn = b_ih[2 * HH + j];
    const float bhn = b_hh[2 * HH + j];

    float h = 0.0f;
    const float* xblk = x + (size_t)b0 * (TT * II);

    for (int c = 0; c < NCHUNK; ++c) {
        const int t0 = c * TC;
        __syncthreads();  // previous chunk's reads done
#pragma unroll
        for (int it = 0; it < (16 * TC * II) / 256; ++it) {
            int f  = tid + it * 256;
            int bl = f / (TC * II);
            int r  = f - bl * (TC * II);
            float v = xblk[(size_t)bl * (TT * II) + (size_t)t0 * II + r];
            int t  = r / II;
            int i  = r - t * II;
            if (i < 4) ((float*)&lds_x4[bl][t])[i] = v;
            else       lds_x1[bl][t] = v;
        }
        __syncthreads();

        float4 xv = lds_x4[g][0];
        float  xe = lds_x1[g][0];

#pragma unroll 4
        for (int s = 0; s < TC; ++s) {
            // prefetch next step's x (clamped at chunk end)
            const int sn = (s + 1 < TC) ? s + 1 : s;
            float4 xvn = lds_x4[g][sn];
            float  xen = lds_x1[g][sn];

            // h-part matvec via DPP rotations, parity-split accumulators
            float ar0 = brz, az0 = bzz, an0 = bhn;
            float ar1 = 0.0f, az1 = 0.0f, an1 = 0.0f;
            ar0 = fmaf(wr[0], h, ar0);
            az0 = fmaf(wz[0], h, az0);
            an0 = fmaf(wn[0], h, an0);
#define GRUROT(R, AR, AZ, AN)                  \
            {                                  \
                float hr = rot16<R>(h);        \
                AR = fmaf(wr[R], hr, AR);      \
                AZ = fmaf(wz[R], hr, AZ);      \
                AN = fmaf(wn[R], hr, AN);      \
            }
            GRUROT(1,  ar1, az1, an1)
            GRUROT(2,  ar0, az0, an0)
            GRUROT(3,  ar1, az1, an1)
            GRUROT(4,  ar0, az0, an0)
            GRUROT(5,  ar1, az1, an1)
            GRUROT(6,  ar0, az0, an0)
            GRUROT(7,  ar1, az1, an1)
            GRUROT(8,  ar0, az0, an0)
            GRUROT(9,  ar1, az1, an1)
            GRUROT(10, ar0, az0, an0)
            GRUROT(11, ar1, az1, an1)
            GRUROT(12, ar0, az0, an0)
            GRUROT(13, ar1, az1, an1)
            GRUROT(14, ar0, az0, an0)
            GRUROT(15, ar1, az1, an1)
#undef GRUROT

            // x-part (independent of h)
            float anx = bxn;
            ar1 = dot4(wir, xv, ar1);  ar1 = fmaf(wir4, xe, ar1);
            az1 = dot4(wiz, xv, az1);  az1 = fmaf(wiz4, xe, az1);
            anx = dot4(win, xv, anx);  anx = fmaf(win4, xe, anx);

            float ar  = ar0 + ar1;
            float az  = az0 + az1;
            float anh = an0 + an1;

            float r = fast_sigmoid(ar);
            float z = fast_sigmoid(az);
            float n = fast_tanh(fmaf(r, anh, anx));
            h = fmaf(z, h - n, n);   // (1-z)*n + z*h

            xv = xvn; xe = xen;
        }
    }

    // ---- out[b] = dot(W_fc, h) + b_fc ----
    float w = h * W_fc[j];
    w += __shfl_xor(w, 1);
    w += __shfl_xor(w, 2);
    w += __shfl_xor(w, 4);
    w += __shfl_xor(w, 8);
    if (j == 0) out[b] = w + b_fc[0];
}

extern "C" void kernel_launch(void* const* d_in, const int* in_sizes, int n_in,
                              void* d_out, int out_size, void* d_ws, size_t ws_size,
                              hipStream_t stream) {
    const float* x    = (const float*)d_in[0];
    const float* W_ih = (const float*)d_in[1];
    const float* W_hh = (const float*)d_in[2];
    const float* b_ih = (const float*)d_in[3];
    const float* b_hh = (const float*)d_in[4];
    const float* W_fc = (const float*)d_in[5];
    const float* b_fc = (const float*)d_in[6];
    float* out = (float*)d_out;

    dim3 grid(BB / 16);
    dim3 block(256);
    gru_fwd_kernel<<<grid, block, 0, stream>>>(x, W_ih, W_hh, b_ih, b_hh, W_fc, b_fc, out);
}

// Round 3
// 185.798 us; speedup vs baseline: 1.2272x; 1.2272x over previous
//
#include <hip/hip_runtime.h>

#define BB 8192
#define TT 512
#define II 5
#define HH 16

typedef _Float16 half_t;
typedef _Float16 half4 __attribute__((ext_vector_type(4)));
typedef float floatx4 __attribute__((ext_vector_type(4)));

__device__ __forceinline__ float fast_sigmoid(float x) {
    float e = __builtin_amdgcn_exp2f(x * -1.4426950408889634f);
    return __builtin_amdgcn_rcpf(1.0f + e);
}
__device__ __forceinline__ float fast_tanh(float x) {
    float e = __builtin_amdgcn_exp2f(x * 2.8853900817779268f);
    return fmaf(-2.0f, __builtin_amdgcn_rcpf(e + 1.0f), 1.0f);
}

// Per-wave GRU: 16 batches per 64-lane wave.
// MFMA 16x16x16 f16:  A: row=lane&15, k=4*(lane>>4)+j
//                     B: col=lane&15, k=4*(lane>>4)+j
//                     C/D: col=lane&15, row=4*(lane>>4)+i   (m89-verified)
// D layout == B layout => gate output feeds next step's B operand with no
// cross-lane movement.
__global__ __launch_bounds__(64)
void gru_fwd_kernel(const float* __restrict__ x,
                    const float* __restrict__ W_ih,
                    const float* __restrict__ W_hh,
                    const float* __restrict__ b_ih,
                    const float* __restrict__ b_hh,
                    const float* __restrict__ W_fc,
                    const float* __restrict__ b_fc,
                    float* __restrict__ out) {
    const int lane = threadIdx.x;   // 0..63
    const int jb   = lane & 15;     // batch within tile; also A-row index
    const int q    = lane >> 4;     // k-group
    const int b0   = blockIdx.x * 16;

    // ---- A-fragments (resident): W_hh gate rows; W_ih rows padded to K=16
    half4 wa_r, wa_z, wa_n, wx_r, wx_z, wx_n;
#pragma unroll
    for (int j = 0; j < 4; ++j) {
        int k = 4 * q + j;
        wa_r[j] = (half_t)W_hh[(0 * HH + jb) * HH + k];
        wa_z[j] = (half_t)W_hh[(1 * HH + jb) * HH + k];
        wa_n[j] = (half_t)W_hh[(2 * HH + jb) * HH + k];
        float vr = (k < II) ? W_ih[(0 * HH + jb) * II + k] : 0.0f;
        float vz = (k < II) ? W_ih[(1 * HH + jb) * II + k] : 0.0f;
        float vn = (k < II) ? W_ih[(2 * HH + jb) * II + k] : 0.0f;
        wx_r[j] = (half_t)vr; wx_z[j] = (half_t)vz; wx_n[j] = (half_t)vn;
    }

    // ---- bias C-fragments: row = 4q+i (uniform across batch columns)
    floatx4 cb_r, cb_z, cb_xn, cb_hn;
#pragma unroll
    for (int i = 0; i < 4; ++i) {
        int r = 4 * q + i;
        cb_r[i]  = b_ih[r] + b_hh[r];                    // reset: both biases
        cb_z[i]  = b_ih[HH + r] + b_hh[HH + r];          // update: both biases
        cb_xn[i] = b_ih[2 * HH + r];                     // n, input side
        cb_hn[i] = b_hh[2 * HH + r];                     // n, hidden side
    }

    // ---- loop-carried state
    half4 bh = {};            // h as next-step B fragment (f16)
    float hf0 = 0.0f, hf1 = 0.0f, hf2 = 0.0f, hf3 = 0.0f;  // h rows 4q+i (f32)

    const float* px = x + (size_t)(b0 + jb) * TT * II;

    floatx4 rA = {}, rB = {};
    float   eA = 0.0f, eB = 0.0f;

    // prologue: raw x(t=0)
    if (q == 0)      rA = *(const floatx4*)px;
    else if (q == 1) eA = px[4];

#define MAKE_BX(BX, RV, EV)                                                   \
    half4 BX = {};                                                            \
    if (q == 0) { BX[0] = (half_t)RV[0]; BX[1] = (half_t)RV[1];               \
                  BX[2] = (half_t)RV[2]; BX[3] = (half_t)RV[3]; }             \
    else if (q == 1) { BX[0] = (half_t)EV; }

#define STEP(RV, EV)                                                          \
    {                                                                         \
        MAKE_BX(bx, RV, EV)                                                   \
        floatx4 cx_r = __builtin_amdgcn_mfma_f32_16x16x16f16(wx_r, bx, cb_r, 0, 0, 0); \
        floatx4 cx_z = __builtin_amdgcn_mfma_f32_16x16x16f16(wx_z, bx, cb_z, 0, 0, 0); \
        floatx4 cx_n = __builtin_amdgcn_mfma_f32_16x16x16f16(wx_n, bx, cb_xn, 0, 0, 0); \
        floatx4 d_r  = __builtin_amdgcn_mfma_f32_16x16x16f16(wa_r, bh, cx_r, 0, 0, 0); \
        floatx4 d_z  = __builtin_amdgcn_mfma_f32_16x16x16f16(wa_z, bh, cx_z, 0, 0, 0); \
        floatx4 d_n  = __builtin_amdgcn_mfma_f32_16x16x16f16(wa_n, bh, cb_hn, 0, 0, 0); \
        {                                                                     \
            float r0 = fast_sigmoid(d_r[0]);                                  \
            float z0 = fast_sigmoid(d_z[0]);                                  \
            float n0 = fast_tanh(fmaf(r0, d_n[0], cx_n[0]));                  \
            hf0 = fmaf(z0, hf0 - n0, n0);  bh[0] = (half_t)hf0;               \
            float r1 = fast_sigmoid(d_r[1]);                                  \
            float z1 = fast_sigmoid(d_z[1]);                                  \
            float n1 = fast_tanh(fmaf(r1, d_n[1], cx_n[1]));                  \
            hf1 = fmaf(z1, hf1 - n1, n1);  bh[1] = (half_t)hf1;               \
            float r2 = fast_sigmoid(d_r[2]);                                  \
            float z2 = fast_sigmoid(d_z[2]);                                  \
            float n2 = fast_tanh(fmaf(r2, d_n[2], cx_n[2]));                  \
            hf2 = fmaf(z2, hf2 - n2, n2);  bh[2] = (half_t)hf2;               \
            float r3 = fast_sigmoid(d_r[3]);                                  \
            float z3 = fast_sigmoid(d_z[3]);                                  \
            float n3 = fast_tanh(fmaf(r3, d_n[3], cx_n[3]));                  \
            hf3 = fmaf(z3, hf3 - n3, n3);  bh[3] = (half_t)hf3;               \
        }                                                                     \
    }

    for (int t = 0; t < TT; t += 2) {
        // prefetch x(t+1)
        const float* p1 = px + (size_t)(t + 1) * II;
        if (q == 0)      rB = *(const floatx4*)p1;
        else if (q == 1) eB = p1[4];

        STEP(rA, eA)      // step t

        // prefetch x(t+2) (clamped at end; value unused then)
        const int t2 = (t + 2 < TT) ? t + 2 : t;
        const float* p2 = px + (size_t)t2 * II;
        if (q == 0)      rA = *(const floatx4*)p2;
        else if (q == 1) eA = p2[4];

        STEP(rB, eB)      // step t+1
    }
#undef STEP
#undef MAKE_BX

    // ---- out[b] = dot(W_fc, h) + b_fc : partial over rows 4q..4q+4,
    // then reduce across the 4 k-groups (lanes jb, jb+16, jb+32, jb+48).
    float p = hf0 * W_fc[4 * q + 0];
    p = fmaf(hf1, W_fc[4 * q + 1], p);
    p = fmaf(hf2, W_fc[4 * q + 2], p);
    p = fmaf(hf3, W_fc[4 * q + 3], p);
    p += __shfl_xor(p, 16);
    p += __shfl_xor(p, 32);
    if (q == 0) out[b0 + jb] = p + b_fc[0];
}

extern "C" void kernel_launch(void* const* d_in, const int* in_sizes, int n_in,
                              void* d_out, int out_size, void* d_ws, size_t ws_size,
                              hipStream_t stream) {
    const float* x    = (const float*)d_in[0];
    const float* W_ih = (const float*)d_in[1];
    const float* W_hh = (const float*)d_in[2];
    const float* b_ih = (const float*)d_in[3];
    const float* b_hh = (const float*)d_in[4];
    const float* W_fc = (const float*)d_in[5];
    const float* b_fc = (const float*)d_in[6];
    float* out = (float*)d_out;

    dim3 grid(BB / 16);   // one 64-lane wave per 16 batches
    dim3 block(64);
    gru_fwd_kernel<<<grid, block, 0, stream>>>(x, W_ih, W_hh, b_ih, b_hh, W_fc, b_fc, out);
}

// Round 5
// 148.353 us; speedup vs baseline: 1.5370x; 1.2524x over previous
//
#include <hip/hip_runtime.h>

#define BB 8192
#define TT 512
#define II 5
#define HH 16

typedef _Float16 half_t;
typedef _Float16 half4 __attribute__((ext_vector_type(4)));
typedef __fp16 fp16x2 __attribute__((ext_vector_type(2)));   // cvt_pkrtz result type
typedef float floatx4 __attribute__((ext_vector_type(4)));
typedef float floatx2 __attribute__((ext_vector_type(2)));

__device__ __forceinline__ float fast_sigmoid(float x) {
    float e = __builtin_amdgcn_exp2f(x * -1.4426950408889634f);
    return __builtin_amdgcn_rcpf(1.0f + e);
}
__device__ __forceinline__ float fast_tanh(float x) {
    float e = __builtin_amdgcn_exp2f(x * 2.8853900817779268f);
    return fmaf(-2.0f, __builtin_amdgcn_rcpf(e + 1.0f), 1.0f);
}

// Per-wave GRU: 16 batches per 64-lane wave.
// MFMA 16x16x16 f16: B col=lane&15(batch), k=4q+j ; C/D col=lane&15, row=4q+i.
// D layout == B layout => gate output feeds next step's B operand in-lane.
// x is register-prefetched 16 steps deep (ping-pong) to cover HBM latency.
__global__ __launch_bounds__(64)
void gru_fwd_kernel(const float* __restrict__ x,
                    const float* __restrict__ W_ih,
                    const float* __restrict__ W_hh,
                    const float* __restrict__ b_ih,
                    const float* __restrict__ b_hh,
                    const float* __restrict__ W_fc,
                    const float* __restrict__ b_fc,
                    float* __restrict__ out) {
    const int lane = threadIdx.x;   // 0..63
    const int jb   = lane & 15;     // batch within tile (B/D column, A row)
    const int q    = lane >> 4;     // k-group
    const int b0   = blockIdx.x * 16;

    // ---- resident A-fragments: W_hh gate rows; W_ih rows zero-padded to K=16
    half4 wa_r, wa_z, wa_n, wx_r, wx_z, wx_n;
#pragma unroll
    for (int j = 0; j < 4; ++j) {
        int k = 4 * q + j;
        wa_r[j] = (half_t)W_hh[(0 * HH + jb) * HH + k];
        wa_z[j] = (half_t)W_hh[(1 * HH + jb) * HH + k];
        wa_n[j] = (half_t)W_hh[(2 * HH + jb) * HH + k];
        float vr = (k < II) ? W_ih[(0 * HH + jb) * II + k] : 0.0f;
        float vz = (k < II) ? W_ih[(1 * HH + jb) * II + k] : 0.0f;
        float vn = (k < II) ? W_ih[(2 * HH + jb) * II + k] : 0.0f;
        wx_r[j] = (half_t)vr; wx_z[j] = (half_t)vz; wx_n[j] = (half_t)vn;
    }

    // ---- bias C-fragments (row = 4q+i, uniform over batch columns)
    floatx4 cb_r, cb_z, cb_xn, cb_hn;
#pragma unroll
    for (int i = 0; i < 4; ++i) {
        int r = 4 * q + i;
        cb_r[i]  = b_ih[r] + b_hh[r];
        cb_z[i]  = b_ih[HH + r] + b_hh[HH + r];
        cb_xn[i] = b_ih[2 * HH + r];
        cb_hn[i] = b_hh[2 * HH + r];
    }

    // ---- loop-carried state
    half4 bh = {};                                        // h as B-fragment
    float hf0 = 0.0f, hf1 = 0.0f, hf2 = 0.0f, hf3 = 0.0f; // h rows 4q+i (f32)

    const float* px = x + (size_t)(b0 + jb) * (TT * II);  // same for all q

    // x register buffers: 16 steps/block = 8 windows x 5 float2 (10 floats/2 steps)
    floatx2 XA[8][5], XB[8][5];

    // Load one 16-step block; clamp base so tail prefetch stays in-bounds.
#define LOADBLK(BUF, T0)                                                      \
    do {                                                                      \
        const int tc_ = ((T0) <= TT - 16) ? (T0) : (TT - 16);                 \
        _Pragma("unroll")                                                     \
        for (int w_ = 0; w_ < 8; ++w_) {                                      \
            const float* pw_ = px + (size_t)(tc_ + 2 * w_) * II;              \
            _Pragma("unroll")                                                 \
            for (int p_ = 0; p_ < 5; ++p_)                                    \
                BUF[w_][p_] = *(const floatx2*)(pw_ + 2 * p_);                \
        }                                                                     \
    } while (0)

    // One GRU step; F0..F4 are this step's x[0..4] (f32, lane-redundant).
#define STEP(F0, F1, F2, F3, F4)                                              \
    do {                                                                      \
        half4 bx = {};                                                        \
        if (q == 0) { bx[0] = (half_t)(F0); bx[1] = (half_t)(F1);             \
                      bx[2] = (half_t)(F2); bx[3] = (half_t)(F3); }           \
        else if (q == 1) { bx[0] = (half_t)(F4); }                            \
        floatx4 cx_r = __builtin_amdgcn_mfma_f32_16x16x16f16(wx_r, bx, cb_r, 0, 0, 0); \
        floatx4 cx_z = __builtin_amdgcn_mfma_f32_16x16x16f16(wx_z, bx, cb_z, 0, 0, 0); \
        floatx4 cx_n = __builtin_amdgcn_mfma_f32_16x16x16f16(wx_n, bx, cb_xn, 0, 0, 0); \
        floatx4 d_r  = __builtin_amdgcn_mfma_f32_16x16x16f16(wa_r, bh, cx_r, 0, 0, 0); \
        floatx4 d_z  = __builtin_amdgcn_mfma_f32_16x16x16f16(wa_z, bh, cx_z, 0, 0, 0); \
        floatx4 d_n  = __builtin_amdgcn_mfma_f32_16x16x16f16(wa_n, bh, cb_hn, 0, 0, 0); \
        float r0 = fast_sigmoid(d_r[0]), z0 = fast_sigmoid(d_z[0]);           \
        float n0 = fast_tanh(fmaf(r0, d_n[0], cx_n[0]));                      \
        hf0 = fmaf(z0, hf0 - n0, n0);                                         \
        float r1 = fast_sigmoid(d_r[1]), z1 = fast_sigmoid(d_z[1]);           \
        float n1 = fast_tanh(fmaf(r1, d_n[1], cx_n[1]));                      \
        hf1 = fmaf(z1, hf1 - n1, n1);                                         \
        float r2 = fast_sigmoid(d_r[2]), z2 = fast_sigmoid(d_z[2]);           \
        float n2 = fast_tanh(fmaf(r2, d_n[2], cx_n[2]));                      \
        hf2 = fmaf(z2, hf2 - n2, n2);                                         \
        float r3 = fast_sigmoid(d_r[3]), z3 = fast_sigmoid(d_z[3]);           \
        float n3 = fast_tanh(fmaf(r3, d_n[3], cx_n[3]));                      \
        hf3 = fmaf(z3, hf3 - n3, n3);                                         \
        fp16x2 lo_ = __builtin_amdgcn_cvt_pkrtz(hf0, hf1);                    \
        fp16x2 hi_ = __builtin_amdgcn_cvt_pkrtz(hf2, hf3);                    \
        bh[0] = (half_t)lo_[0]; bh[1] = (half_t)lo_[1];                       \
        bh[2] = (half_t)hi_[0]; bh[3] = (half_t)hi_[1];                       \
    } while (0)

    // 16 steps from one buffer: window w holds steps {2w, 2w+1} as 10 floats.
#define COMPBLK(BUF)                                                          \
    do {                                                                      \
        _Pragma("unroll")                                                     \
        for (int w_ = 0; w_ < 8; ++w_) {                                      \
            STEP(BUF[w_][0][0], BUF[w_][0][1], BUF[w_][1][0],                 \
                 BUF[w_][1][1], BUF[w_][2][0]);                               \
            STEP(BUF[w_][2][1], BUF[w_][3][0], BUF[w_][3][1],                 \
                 BUF[w_][4][0], BUF[w_][4][1]);                               \
        }                                                                     \
    } while (0)

    LOADBLK(XA, 0);
    for (int it = 0; it < TT / 32; ++it) {      // 32 steps per iteration
        const int t0 = it * 32;
        LOADBLK(XB, t0 + 16);   // in flight while XA computes
        COMPBLK(XA);
        LOADBLK(XA, t0 + 32);   // in flight while XB computes (tail-clamped)
        COMPBLK(XB);
    }
#undef LOADBLK
#undef STEP
#undef COMPBLK

    // ---- out[b] = dot(W_fc, h) + b_fc ; reduce across the 4 k-groups
    float p = hf0 * W_fc[4 * q + 0];
    p = fmaf(hf1, W_fc[4 * q + 1], p);
    p = fmaf(hf2, W_fc[4 * q + 2], p);
    p = fmaf(hf3, W_fc[4 * q + 3], p);
    p += __shfl_xor(p, 16);
    p += __shfl_xor(p, 32);
    if (q == 0) out[b0 + jb] = p + b_fc[0];
}

extern "C" void kernel_launch(void* const* d_in, const int* in_sizes, int n_in,
                              void* d_out, int out_size, void* d_ws, size_t ws_size,
                              hipStream_t stream) {
    const float* x    = (const float*)d_in[0];
    const float* W_ih = (const float*)d_in[1];
    const float* W_hh = (const float*)d_in[2];
    const float* b_ih = (const float*)d_in[3];
    const float* b_hh = (const float*)d_in[4];
    const float* W_fc = (const float*)d_in[5];
    const float* b_fc = (const float*)d_in[6];
    float* out = (float*)d_out;

    dim3 grid(BB / 16);   // one 64-lane wave per 16 batches
    dim3 block(64);
    gru_fwd_kernel<<<grid, block, 0, stream>>>(x, W_ih, W_hh, b_ih, b_hh, W_fc, b_fc, out);
}